// Round 4
// baseline (1032.847 us; speedup 1.0000x reference)
//
#include <hip/hip_runtime.h>
#include <hip/hip_bf16.h>
#include <stdint.h>

#define N_NODES 50000
#define N_EDGES 500000
#define R_REL 8
#define HID 128
#define KIN 128              // input features per slab
#define KOUT 1152            // 9*128: concat K dim (W_0..W_7 | root)
#define NUM_GRAPHS 64
#define NUM_CLASSES 16

#define BN 32                // dst-nodes per fused block
#define LDA 1160             // A row stride (elements) for both fp32 Af and bf16 As
#define NBLK 1563            // ceil(50000/32)

typedef __attribute__((ext_vector_type(8))) short bf16x8;
typedef __attribute__((ext_vector_type(4))) float f32x4;

// ---------- helpers ----------
__device__ __forceinline__ uint16_t f2bf(float f) {
  uint32_t u = __float_as_uint(f);
  u += 0x7FFFu + ((u >> 16) & 1u);   // RNE
  return (uint16_t)(u >> 16);
}
__device__ __forceinline__ float bf2f(uint32_t b) {
  return __uint_as_float(b << 16);
}
__device__ __forceinline__ uint32_t pack2bf(float a, float b) {
  return (uint32_t)f2bf(a) | ((uint32_t)f2bf(b) << 16);
}
#define MFMA(a, b, c) __builtin_amdgcn_mfma_f32_16x16x32_bf16((a), (b), (c), 0, 0, 0)

// ---------- merged prep: hist | bounds | weightprep (LDS-staged) | x->bf16 ----------
#define HIST_B 1954
#define BND_B 196
#define WP_B 72             // 2 matrices x 36 kc-chunks
#define CVT_B 3125          // N_NODES*HID/8 / 256
__global__ __launch_bounds__(256) void k_prep(const int* __restrict__ ei, const int* __restrict__ et,
                                              int* __restrict__ deg,
                                              const int* __restrict__ batch,
                                              int* __restrict__ gs, int* __restrict__ ge,
                                              const float* __restrict__ W1, const float* __restrict__ root1,
                                              uint16_t* __restrict__ Wf1,
                                              const float* __restrict__ W2, const float* __restrict__ root2,
                                              uint16_t* __restrict__ Wf2,
                                              const float* __restrict__ x, uint16_t* __restrict__ xb) {
  int b = blockIdx.x;
  int t = threadIdx.x;
  if (b < HIST_B) {                                 // per-dst edge histogram (50K buckets)
    int i = b * 256 + t;
    if (i < N_EDGES) atomicAdd(&deg[ei[N_EDGES + i]], 1);
    return;
  }
  b -= HIST_B;
  if (b < BND_B) {                                  // graph boundaries (batch sorted)
    int i = b * 256 + t;
    if (i < N_NODES) {
      int g = batch[i];
      if (i == 0) gs[g] = 0;
      else { int pg = batch[i - 1]; if (pg != g) { ge[pg] = i; gs[g] = i; } }
      if (i == N_NODES - 1) ge[g] = N_NODES;
    }
    return;
  }
  b -= BND_B;
  if (b < WP_B) {
    // weight prep, LDS-staged: block handles one kc-chunk (32 K-rows x 128 cols) of one matrix.
    // Coalesced reads of W rows -> LDS (padded) -> coalesced frag writes.
    __shared__ float lw[32 * 129];
    const float* W    = (b < 36) ? W1 : W2;
    const float* root = (b < 36) ? root1 : root2;
    uint16_t*    Wf   = (b < 36) ? Wf1 : Wf2;
    int kc = (b < 36) ? b : b - 36;
    #pragma unroll
    for (int j = 0; j < 4; ++j) {
      int fi = j * 256 + t;                  // float4 slot over 32 rows x 32 f4
      int row = fi >> 5, c4 = fi & 31;
      int kk = kc * 32 + row;
      int s = kk >> 7, k = kk & 127;
      const float* src = (s < R_REL) ? (W + ((size_t)s * KIN + k) * HID) : (root + (size_t)k * HID);
      float4 v = *(const float4*)(src + c4 * 4);
      lw[row * 129 + c4 * 4 + 0] = v.x;
      lw[row * 129 + c4 * 4 + 1] = v.y;
      lw[row * 129 + c4 * 4 + 2] = v.z;
      lw[row * 129 + c4 * 4 + 3] = v.w;
    }
    __syncthreads();
    #pragma unroll
    for (int p = 0; p < 2; ++p) {
      int slot = p * 256 + t;                // 8 frags x 64 lanes
      int nt = slot >> 6, L = slot & 63;
      int quad = L >> 4, l16 = L & 15;
      uint16_t tmp[8];
      #pragma unroll
      for (int e = 0; e < 8; ++e)
        tmp[e] = f2bf(lw[(quad * 8 + e) * 129 + nt * 16 + l16]);
      uint4 o;
      o.x = (uint32_t)tmp[0] | ((uint32_t)tmp[1] << 16);
      o.y = (uint32_t)tmp[2] | ((uint32_t)tmp[3] << 16);
      o.z = (uint32_t)tmp[4] | ((uint32_t)tmp[5] << 16);
      o.w = (uint32_t)tmp[6] | ((uint32_t)tmp[7] << 16);
      *(uint4*)(Wf + ((size_t)(kc * 8 + nt) * 512 + (size_t)L * 8)) = o;
    }
    return;
  }
  b -= WP_B;
  {                                                 // x (fp32) -> xb (bf16), 8 elems/thread
    int i = b * 256 + t;                            // < 800000 exact
    const float4* p = (const float4*)x + (size_t)i * 2;
    float4 a = p[0], c = p[1];
    uint4 o;
    o.x = pack2bf(a.x, a.y); o.y = pack2bf(a.z, a.w);
    o.z = pack2bf(c.x, c.y); o.w = pack2bf(c.z, c.w);
    *(uint4*)(xb + (size_t)i * 8) = o;
  }
}

// ---------- scans over 50K dst buckets ----------
__global__ __launch_bounds__(256) void k_scan1(const int* __restrict__ deg, int* __restrict__ offs,
                                               int* __restrict__ bsum) {
  __shared__ int sh[256];
  int t = threadIdx.x;
  int base = blockIdx.x * 1024 + t * 4;
  int v[4]; int s = 0;
  #pragma unroll
  for (int i = 0; i < 4; ++i) { int idx = base + i; v[i] = (idx < N_NODES) ? deg[idx] : 0; s += v[i]; }
  sh[t] = s;
  __syncthreads();
  for (int d = 1; d < 256; d <<= 1) {
    int add = (t >= d) ? sh[t - d] : 0;
    __syncthreads();
    sh[t] += add;
    __syncthreads();
  }
  int run = sh[t] - s;
  if (t == 255) bsum[blockIdx.x] = sh[255];
  #pragma unroll
  for (int i = 0; i < 4; ++i) { int idx = base + i; if (idx < N_NODES) offs[idx] = run; run += v[i]; }
}

__global__ __launch_bounds__(512) void k_scan2(int* __restrict__ bsum, int nb) {
  __shared__ int sh[512];
  int t = threadIdx.x;
  int v = (t < nb) ? bsum[t] : 0;
  sh[t] = v;
  __syncthreads();
  for (int d = 1; d < 512; d <<= 1) {
    int add = (t >= d) ? sh[t - d] : 0;
    __syncthreads();
    sh[t] += add;
    __syncthreads();
  }
  if (t < nb) bsum[t] = sh[t] - v;   // exclusive
}

__global__ __launch_bounds__(256) void k_scan3(int* __restrict__ offs, int* __restrict__ nxt,
                                               const int* __restrict__ bsum) {
  int i = blockIdx.x * 256 + threadIdx.x;
  if (i < N_NODES) {
    int o = offs[i] + bsum[i >> 10];
    offs[i] = o;
    nxt[i] = o;
  }
  if (i == 0) offs[N_NODES] = N_EDGES;
}

// scatter: bucket edges by dst; epack = src | rel<<16 | (dst&31)<<19
__global__ __launch_bounds__(256) void k_scatter(const int* __restrict__ ei, const int* __restrict__ et,
                                                 int* __restrict__ nxt, uint32_t* __restrict__ epack) {
  int i = blockIdx.x * 256 + threadIdx.x;
  if (i < N_EDGES) {
    int rel = et[i];
    int dst = ei[N_EDGES + i];
    int p = atomicAdd(&nxt[dst], 1);
    epack[p] = (uint32_t)ei[i] | ((uint32_t)rel << 16) | ((uint32_t)(dst & 31) << 19);
  }
}

// ---------- fused layer: aggregate(LDS-atomic) -> normalize/convert -> split-K MFMA ----------
// Block = 32 dst nodes, 1024 threads (16 waves), 1 block/CU (149.5 KB LDS), 16 waves/CU.
// Phase 1: all 16 waves stream the block's edge range in balanced chunks; per edge:
//   wave-uniform slab address (SALU), 2 ds_add_f32 per lane into fp32 Af[loc][rel*128+2L..],
//   1-lane ds_add count. No ordering/flush/branch-tree logic at all.
// Convert: reg-staged in-place Af fp32 -> As bf16 with 1/cnt mean normalize.
// Phase 2: split-K GEMM out[32,128] = As[32,1152] @ Wcat; wave=(nt=w&7, khalf=w>>3),
//   18 kc each, cross-half reduce through free upper LDS.
template<int MODE>
__global__ __launch_bounds__(1024, 4) void k_fused(const uint16_t* __restrict__ hin,
                                                   const uint32_t* __restrict__ epack,
                                                   const int* __restrict__ offs,
                                                   const uint16_t* __restrict__ Wf,
                                                   const float* __restrict__ bias,
                                                   void* __restrict__ hout,
                                                   float* __restrict__ psum,
                                                   const int* __restrict__ batch) {
  __shared__ __align__(16) float Af[BN * LDA + 256];   // fp32 accum + cnt tail
  uint16_t* As = (uint16_t*)Af;                        // bf16 [32][1160] (in-place, reg-staged)
  float* cnt = Af + BN * LDA;                          // [32][8]
  float* scratch = (float*)((char*)Af + (size_t)BN * LDA * 2);  // 16 KB split-K scratch (free after convert)

  int t = threadIdx.x;
  int w = __builtin_amdgcn_readfirstlane(t >> 6);      // 0..15
  int L = t & 63;
  int quad = L >> 4, l16 = L & 15;
  int node0 = blockIdx.x * BN;
  int nt = w & 7, kh = w >> 3;

  // hoist first two B-frags (L2-hot; in flight across phase 1)
  const uint16_t* wpk = Wf + ((size_t)(kh * 18 * 8 + nt)) * 512 + (size_t)L * 8;
  bf16x8 b0 = *(const bf16x8*)(wpk);
  bf16x8 b1 = *(const bf16x8*)(wpk + 4096);

  // ---- zero rel-slabs + cnt; load root slab (bf16 -> fp32) ----
  {
    f32x4 z = {0.f, 0.f, 0.f, 0.f};
    #pragma unroll
    for (int j = 0; j < 8; ++j) {                    // 32 rows x 256 f4 (k<1024)
      int fi = j * 1024 + t;
      int r = fi >> 8, k4 = fi & 255;
      *(f32x4*)(Af + (size_t)r * LDA + k4 * 4) = z;
    }
    if (t < 256) cnt[t] = 0.f;
    int r = t >> 5, d0 = (t & 31) * 4;
    int n = node0 + r;
    f32x4 rv = {0.f, 0.f, 0.f, 0.f};
    if (n < N_NODES) {
      uint32_t u0 = *(const uint32_t*)(hin + (size_t)n * HID + d0);
      uint32_t u1 = *(const uint32_t*)(hin + (size_t)n * HID + d0 + 2);
      rv[0] = bf2f(u0 & 0xFFFFu); rv[1] = bf2f(u0 >> 16);
      rv[2] = bf2f(u1 & 0xFFFFu); rv[3] = bf2f(u1 >> 16);
    }
    *(f32x4*)(Af + (size_t)r * LDA + R_REL * HID + d0) = rv;
  }
  __syncthreads();

  // ---- phase 1: cooperative edge stream with LDS-atomic accumulate ----
  {
    int s0 = offs[node0];
    int s1 = offs[min(node0 + BN, N_NODES)];
    int ce = s1 - s0;
    int e0 = s0 + ((ce * w) >> 4);
    int e1 = s0 + ((ce * (w + 1)) >> 4);
    int lsel = L & 15;
    uint32_t pv = epack[e0 + lsel];                  // lanes 0..15 carry next 16 edges (ws padded)
    #pragma unroll 1
    for (int g = e0; g < e1; g += 16) {
      uint32_t pc = pv;
      int m = min(16, e1 - g);
      pv = epack[g + 16 + lsel];                     // prefetch next chunk
      uint32_t vv[16], sv[16];
      #pragma unroll
      for (int i = 0; i < 16; ++i) if (i < m) {
        uint32_t s = (uint32_t)__builtin_amdgcn_readlane((int)pc, i);   // SGPR
        sv[i] = s;
        vv[i] = *(const uint32_t*)(hin + (size_t)(s & 0xFFFFu) * HID + 2u * (uint32_t)L);
      }
      #pragma unroll
      for (int i = 0; i < 16; ++i) if (i < m) {
        uint32_t s = sv[i];
        int rel = (int)((s >> 16) & 7u);
        int loc = (int)(s >> 19);
        float* slab = Af + (size_t)loc * LDA + rel * HID + 2 * L;
        uint32_t v = vv[i];
        atomicAdd(slab, bf2f(v & 0xFFFFu));
        atomicAdd(slab + 1, bf2f(v >> 16));
        if (L == 0) atomicAdd(&cnt[loc * 8 + rel], 1.0f);
      }
    }
  }
  __syncthreads();

  // ---- convert Af fp32 -> As bf16 with mean normalize (reg-staged, in-place) ----
  {
    f32x4 st[9];
    #pragma unroll
    for (int j = 0; j < 9; ++j) {                    // 32 rows x 288 f4 (k<1152), exact
      int fi = j * 1024 + t;
      int r = fi / 288, k4 = fi - r * 288;
      st[j] = *(const f32x4*)(Af + (size_t)r * LDA + k4 * 4);
    }
    __syncthreads();                                 // all reads done before any write
    #pragma unroll
    for (int j = 0; j < 9; ++j) {
      int fi = j * 1024 + t;
      int r = fi / 288, k4 = fi - r * 288;
      int rel = k4 >> 5;                             // 0..8
      float inv = 1.0f;
      if (rel < R_REL) inv = 1.0f / fmaxf(cnt[r * 8 + rel], 1.0f);
      f32x4 v = st[j];
      uint2 o;
      o.x = pack2bf(v[0] * inv, v[1] * inv);
      o.y = pack2bf(v[2] * inv, v[3] * inv);
      *(uint2*)(As + (size_t)r * LDA + k4 * 4) = o;
    }
  }
  __syncthreads();

  // ---- phase 2: split-K GEMM ----
  f32x4 acc0 = {0.f, 0.f, 0.f, 0.f};
  f32x4 acc1 = {0.f, 0.f, 0.f, 0.f};
  {
    const uint16_t* apk = As + (size_t)l16 * LDA + quad * 8 + kh * 18 * 32;
    bf16x8 a00 = *(const bf16x8*)(apk);
    bf16x8 a01 = *(const bf16x8*)(apk + 16 * LDA);
    #pragma unroll 1
    for (int kc = 0; kc < 16; kc += 2) {
      bf16x8 nb0 = *(const bf16x8*)(wpk + (size_t)(kc + 2) * 4096);
      bf16x8 na0 = *(const bf16x8*)(apk + (kc + 1) * 32);
      bf16x8 na1 = *(const bf16x8*)(apk + (kc + 1) * 32 + 16 * LDA);
      acc0 = MFMA(a00, b0, acc0);
      acc1 = MFMA(a01, b0, acc1);
      b0 = nb0;
      bf16x8 nb1 = *(const bf16x8*)(wpk + (size_t)(kc + 3) * 4096);
      bf16x8 ma0 = *(const bf16x8*)(apk + (kc + 2) * 32);
      bf16x8 ma1 = *(const bf16x8*)(apk + (kc + 2) * 32 + 16 * LDA);
      acc0 = MFMA(na0, b1, acc0);
      acc1 = MFMA(na1, b1, acc1);
      b1 = nb1; a00 = ma0; a01 = ma1;
    }
    bf16x8 ta0 = *(const bf16x8*)(apk + 17 * 32);
    bf16x8 ta1 = *(const bf16x8*)(apk + 17 * 32 + 16 * LDA);
    acc0 = MFMA(a00, b0, acc0);
    acc1 = MFMA(a01, b0, acc1);
    acc0 = MFMA(ta0, b1, acc0);
    acc1 = MFMA(ta1, b1, acc1);
  }

  // ---- split-K reduce via LDS scratch, epilogue by kh==0 waves ----
  if (kh == 1) {
    float* sp = scratch + (size_t)(nt * 2) * 256 + L * 4;
    *(f32x4*)(sp) = acc0;
    *(f32x4*)(sp + 256) = acc1;
  }
  __syncthreads();
  if (kh == 0) {
    const float* sp = scratch + (size_t)(nt * 2) * 256 + L * 4;
    f32x4 o0 = *(const f32x4*)(sp);
    f32x4 o1 = *(const f32x4*)(sp + 256);
    acc0 += o0;
    acc1 += o1;
    int col = nt * 16 + l16;
    float bv = bias[col];
    if (MODE == 0) {
      #pragma unroll
      for (int rg = 0; rg < 4; ++rg) {
        int row = node0 + quad * 4 + rg;
        if (row < N_NODES)
          ((uint16_t*)hout)[(size_t)row * HID + col] = f2bf(fmaxf(acc0[rg] + bv, 0.f));
      }
      #pragma unroll
      for (int rg = 0; rg < 4; ++rg) {
        int row = node0 + 16 + quad * 4 + rg;
        if (row < N_NODES)
          ((uint16_t*)hout)[(size_t)row * HID + col] = f2bf(fmaxf(acc1[rg] + bv, 0.f));
      }
    } else {
      // fused global-mean-pool partials (sum; divide in k_final)
      bool fast = false;
      int gA = 0;
      if (node0 + BN <= N_NODES) {
        gA = batch[node0];
        int gB = batch[node0 + BN - 1];
        fast = (gA == gB);
      }
      if (fast) {
        float s = 0.f;
        #pragma unroll
        for (int rg = 0; rg < 4; ++rg) s += fmaxf(acc0[rg] + bv, 0.f);
        #pragma unroll
        for (int rg = 0; rg < 4; ++rg) s += fmaxf(acc1[rg] + bv, 0.f);
        s += __shfl_xor(s, 16);
        s += __shfl_xor(s, 32);
        if (quad == 0) atomicAdd(&psum[gA * HID + col], s);
      } else {
        int gp = -1; float run = 0.f;
        #pragma unroll
        for (int k = 0; k < 8; ++k) {
          int rg = k & 3;
          int row = node0 + (k >> 2) * 16 + quad * 4 + rg;
          float v = (k < 4) ? acc0[rg] : acc1[rg];
          if (row < N_NODES) {
            int gg = batch[row];
            if (gg != gp) {
              if (gp >= 0) atomicAdd(&psum[gp * HID + col], run);
              run = 0.f; gp = gg;
            }
            run += fmaxf(v + bv, 0.f);
          }
        }
        if (gp >= 0) atomicAdd(&psum[gp * HID + col], run);
      }
    }
  }
}

__global__ __launch_bounds__(1024) void k_final(const float* __restrict__ psum,
                                                const int* __restrict__ gs, const int* __restrict__ ge,
                                                const float* __restrict__ linW, const float* __restrict__ linb,
                                                float* __restrict__ out) {
  int i = threadIdx.x;              // 64*16 = 1024
  int g = i >> 4, c = i & 15;
  float inv = 1.f / fmaxf((float)(ge[g] - gs[g]), 1.f);
  float s = 0.f;
  #pragma unroll 8
  for (int k = 0; k < HID; ++k) s += psum[g * HID + k] * linW[k * NUM_CLASSES + c];
  out[i] = s * inv + linb[c];
}

// ---------- launch ----------
extern "C" void kernel_launch(void* const* d_in, const int* in_sizes, int n_in,
                              void* d_out, int out_size, void* d_ws, size_t ws_size,
                              hipStream_t stream) {
  const float* x     = (const float*)d_in[0];
  const int*   ei    = (const int*)d_in[1];   // [2,E]: [0..E) src, [E..2E) dst
  const int*   et    = (const int*)d_in[2];
  const int*   batch = (const int*)d_in[3];
  const float* W1    = (const float*)d_in[4];
  const float* root1 = (const float*)d_in[5];
  const float* b1    = (const float*)d_in[6];
  const float* W2    = (const float*)d_in[7];
  const float* root2 = (const float*)d_in[8];
  const float* b2    = (const float*)d_in[9];
  const float* linW  = (const float*)d_in[10];
  const float* linb  = (const float*)d_in[11];
  float* out = (float*)d_out;

  char* ws = (char*)d_ws;
  size_t off = 0;
  auto alloc = [&](size_t bytes) -> char* {
    char* p = ws + off;
    off += (bytes + 255) & ~(size_t)255;
    return p;
  };
  // zero-region: deg | gb | psum (contiguous, one memset)
  int*      deg   = (int*)alloc((size_t)N_NODES * 4);
  int*      gb    = (int*)alloc(2 * NUM_GRAPHS * 4);
  float*    psum  = (float*)alloc((size_t)NUM_GRAPHS * HID * 4);
  size_t zbytes = (((size_t)N_NODES * 4 + 255) & ~(size_t)255) + 512 + (size_t)NUM_GRAPHS * HID * 4;
  int*      gs    = gb;
  int*      ge    = gb + NUM_GRAPHS;
  int*      offs  = (int*)alloc((size_t)(N_NODES + 1) * 4);
  int*      nxt   = (int*)alloc((size_t)N_NODES * 4);
  int*      bsum  = (int*)alloc(512 * 4);
  uint32_t* epack = (uint32_t*)alloc((size_t)(N_EDGES + 64) * 4);   // +64: safe prefetch overrun
  uint16_t* Wf1   = (uint16_t*)alloc((size_t)KOUT * KIN * 2);
  uint16_t* Wf2   = (uint16_t*)alloc((size_t)KOUT * KIN * 2);
  uint16_t* xb    = (uint16_t*)alloc((size_t)N_NODES * HID * 2);
  uint16_t* h1b   = (uint16_t*)alloc((size_t)N_NODES * HID * 2);

  hipMemsetAsync(deg, 0, zbytes, stream);

  int nb = (N_NODES + 1023) / 1024;     // 49
  k_prep<<<HIST_B + BND_B + WP_B + CVT_B, 256, 0, stream>>>(
      ei, et, deg, batch, gs, ge, W1, root1, Wf1, W2, root2, Wf2, x, xb);
  k_scan1<<<nb, 256, 0, stream>>>(deg, offs, bsum);
  k_scan2<<<1, 512, 0, stream>>>(bsum, nb);
  k_scan3<<<(N_NODES + 255) / 256, 256, 0, stream>>>(offs, nxt, bsum);
  k_scatter<<<(N_EDGES + 255) / 256, 256, 0, stream>>>(ei, et, nxt, epack);

  // fused layers
  k_fused<0><<<NBLK, 1024, 0, stream>>>(xb,  epack, offs, Wf1, b1, h1b, nullptr, nullptr);
  k_fused<1><<<NBLK, 1024, 0, stream>>>(h1b, epack, offs, Wf2, b2, nullptr, psum, batch);

  k_final<<<1, 1024, 0, stream>>>(psum, gs, ge, linW, linb, out);
}

// Round 5
// 312.742 us; speedup vs baseline: 3.3026x; 3.3026x over previous
//
#include <hip/hip_runtime.h>
#include <hip/hip_bf16.h>
#include <stdint.h>

#define N_NODES 50000
#define N_EDGES 500000
#define R_REL 8
#define HID 128
#define KIN 128              // input features per slab
#define KOUT 1152            // 9*128: concat K dim (W_0..W_7 | root)
#define N8 400000            // N_NODES * R_REL composite buckets
#define NUM_GRAPHS 64
#define NUM_CLASSES 16

#define BN 32                // dst-nodes per fused block
#define LDA 1160             // A row stride in shorts (2320 B)
#define NBLK 1563            // ceil(50000/32)

typedef __attribute__((ext_vector_type(8))) short bf16x8;
typedef __attribute__((ext_vector_type(4))) float f32x4;

// ---------- helpers ----------
__device__ __forceinline__ uint16_t f2bf(float f) {
  uint32_t u = __float_as_uint(f);
  u += 0x7FFFu + ((u >> 16) & 1u);   // RNE
  return (uint16_t)(u >> 16);
}
__device__ __forceinline__ float bf2f(uint32_t b) {
  return __uint_as_float(b << 16);
}
__device__ __forceinline__ uint32_t pack2bf(float a, float b) {
  return (uint32_t)f2bf(a) | ((uint32_t)f2bf(b) << 16);
}
#define MFMA(a, b, c) __builtin_amdgcn_mfma_f32_16x16x32_bf16((a), (b), (c), 0, 0, 0)

// ---------- merged prep: hist | bounds | weightprep (LDS-staged) | x->bf16 ----------
#define HIST_B 1954
#define BND_B 196
#define WP_B 72             // 2 matrices x 36 kc-chunks
#define CVT_B 3125          // N_NODES*HID/8 / 256
__global__ __launch_bounds__(256) void k_prep(const int* __restrict__ ei, const int* __restrict__ et,
                                              int* __restrict__ deg8,
                                              const int* __restrict__ batch,
                                              int* __restrict__ gs, int* __restrict__ ge,
                                              const float* __restrict__ W1, const float* __restrict__ root1,
                                              uint16_t* __restrict__ Wf1,
                                              const float* __restrict__ W2, const float* __restrict__ root2,
                                              uint16_t* __restrict__ Wf2,
                                              const float* __restrict__ x, uint16_t* __restrict__ xb) {
  int b = blockIdx.x;
  int t = threadIdx.x;
  if (b < HIST_B) {                                 // (dst,rel) edge histogram (400K buckets)
    int i = b * 256 + t;
    if (i < N_EDGES) atomicAdd(&deg8[ei[N_EDGES + i] * R_REL + et[i]], 1);
    return;
  }
  b -= HIST_B;
  if (b < BND_B) {                                  // graph boundaries (batch sorted)
    int i = b * 256 + t;
    if (i < N_NODES) {
      int g = batch[i];
      if (i == 0) gs[g] = 0;
      else { int pg = batch[i - 1]; if (pg != g) { ge[pg] = i; gs[g] = i; } }
      if (i == N_NODES - 1) ge[g] = N_NODES;
    }
    return;
  }
  b -= BND_B;
  if (b < WP_B) {
    // weight prep, LDS-staged: block handles one kc-chunk (32 K-rows x 128 cols) of one matrix.
    __shared__ float lw[32 * 129];
    const float* W    = (b < 36) ? W1 : W2;
    const float* root = (b < 36) ? root1 : root2;
    uint16_t*    Wf   = (b < 36) ? Wf1 : Wf2;
    int kc = (b < 36) ? b : b - 36;
    #pragma unroll
    for (int j = 0; j < 4; ++j) {
      int fi = j * 256 + t;                  // float4 slot over 32 rows x 32 f4
      int row = fi >> 5, c4 = fi & 31;
      int kk = kc * 32 + row;
      int s = kk >> 7, k = kk & 127;
      const float* src = (s < R_REL) ? (W + ((size_t)s * KIN + k) * HID) : (root + (size_t)k * HID);
      float4 v = *(const float4*)(src + c4 * 4);
      lw[row * 129 + c4 * 4 + 0] = v.x;
      lw[row * 129 + c4 * 4 + 1] = v.y;
      lw[row * 129 + c4 * 4 + 2] = v.z;
      lw[row * 129 + c4 * 4 + 3] = v.w;
    }
    __syncthreads();
    #pragma unroll
    for (int p = 0; p < 2; ++p) {
      int slot = p * 256 + t;                // 8 frags x 64 lanes
      int nt = slot >> 6, L = slot & 63;
      int quad = L >> 4, l16 = L & 15;
      uint16_t tmp[8];
      #pragma unroll
      for (int e = 0; e < 8; ++e)
        tmp[e] = f2bf(lw[(quad * 8 + e) * 129 + nt * 16 + l16]);
      uint4 o;
      o.x = (uint32_t)tmp[0] | ((uint32_t)tmp[1] << 16);
      o.y = (uint32_t)tmp[2] | ((uint32_t)tmp[3] << 16);
      o.z = (uint32_t)tmp[4] | ((uint32_t)tmp[5] << 16);
      o.w = (uint32_t)tmp[6] | ((uint32_t)tmp[7] << 16);
      *(uint4*)(Wf + ((size_t)(kc * 8 + nt) * 512 + (size_t)L * 8)) = o;
    }
    return;
  }
  b -= WP_B;
  {                                                 // x (fp32) -> xb (bf16), 8 elems/thread
    int i = b * 256 + t;                            // < 800000 exact
    const float4* p = (const float4*)x + (size_t)i * 2;
    float4 a = p[0], c = p[1];
    uint4 o;
    o.x = pack2bf(a.x, a.y); o.y = pack2bf(a.z, a.w);
    o.z = pack2bf(c.x, c.y); o.w = pack2bf(c.z, c.w);
    *(uint4*)(xb + (size_t)i * 8) = o;
  }
}

// ---------- scans over 400K (dst,rel) buckets ----------
__global__ __launch_bounds__(256) void k_scan1(const int* __restrict__ deg8, int* __restrict__ offs8,
                                               int* __restrict__ bsum) {
  __shared__ int sh[256];
  int t = threadIdx.x;
  int base = blockIdx.x * 1024 + t * 4;
  int v[4]; int s = 0;
  #pragma unroll
  for (int i = 0; i < 4; ++i) { int idx = base + i; v[i] = (idx < N8) ? deg8[idx] : 0; s += v[i]; }
  sh[t] = s;
  __syncthreads();
  for (int d = 1; d < 256; d <<= 1) {
    int add = (t >= d) ? sh[t - d] : 0;
    __syncthreads();
    sh[t] += add;
    __syncthreads();
  }
  int run = sh[t] - s;
  if (t == 255) bsum[blockIdx.x] = sh[255];
  #pragma unroll
  for (int i = 0; i < 4; ++i) { int idx = base + i; if (idx < N8) offs8[idx] = run; run += v[i]; }
}

__global__ __launch_bounds__(512) void k_scan2(int* __restrict__ bsum, int nb) {
  __shared__ int sh[512];
  int t = threadIdx.x;
  int v = (t < nb) ? bsum[t] : 0;
  sh[t] = v;
  __syncthreads();
  for (int d = 1; d < 512; d <<= 1) {
    int add = (t >= d) ? sh[t - d] : 0;
    __syncthreads();
    sh[t] += add;
    __syncthreads();
  }
  if (t < nb) bsum[t] = sh[t] - v;   // exclusive
}

__global__ __launch_bounds__(256) void k_scan3(int* __restrict__ offs8, int* __restrict__ nxt,
                                               const int* __restrict__ bsum) {
  int i = blockIdx.x * 256 + threadIdx.x;
  if (i < N8) {
    int o = offs8[i] + bsum[i >> 10];
    offs8[i] = o;
    nxt[i] = o;
  }
  if (i == 0) offs8[N8] = N_EDGES;
}

// scatter into (dst,rel) buckets: stream becomes sorted by (dst,rel).
// epack = src | rel<<16 | (dst&31)<<19  (key = epack>>16 unique per group within a block)
__global__ __launch_bounds__(256) void k_scatter(const int* __restrict__ ei, const int* __restrict__ et,
                                                 int* __restrict__ nxt, uint32_t* __restrict__ epack) {
  int i = blockIdx.x * 256 + threadIdx.x;
  if (i < N_EDGES) {
    int rel = et[i];
    int dst = ei[N_EDGES + i];
    int p = atomicAdd(&nxt[dst * R_REL + rel], 1);
    epack[p] = (uint32_t)ei[i] | ((uint32_t)rel << 16) | ((uint32_t)(dst & 31) << 19);
  }
}

// ---------- fused layer: sorted-stream aggregate -> MFMA transform ----------
// Block = 32 dst nodes, 512 threads (8 waves), LDS As[32][1160] bf16 (74240 B, 2 blocks/CU).
// Phase 1: waves cooperatively stream the block's edge range in flat chunks. Stream is
//   (dst,rel)-sorted; a wave owns every group whose FIRST edge lies in its chunk (skips the
//   continuation prefix, runs past its end to finish the last owned group). Single register
//   accumulator pair + scalar-branch flush (bf16 ds_write with 1/cnt mean) -- no atomics,
//   no per-edge routing. 16-deep gather batches; scalar (SGPR) gather bases via readlane.
// Phase 2: out[32,128] = As[32,1152] @ Wcat; wave w owns cols [w*16,w*16+16); depth-4 B prefetch.
// MODE 0: write bf16 hout. MODE 1: fused global-mean-pool partials into psum.
template<int MODE>
__global__ __launch_bounds__(512, 4) void k_fused(const uint16_t* __restrict__ hin,
                                                  const uint32_t* __restrict__ epack,
                                                  const int* __restrict__ offs8,
                                                  const uint16_t* __restrict__ Wf,
                                                  const float* __restrict__ bias,
                                                  void* __restrict__ hout,
                                                  float* __restrict__ psum,
                                                  const int* __restrict__ batch) {
  __shared__ __align__(16) uint16_t As[BN * LDA];
  int t = threadIdx.x;
  int w = __builtin_amdgcn_readfirstlane(t >> 6);
  int L = t & 63;
  int quad = L >> 4, l16 = L & 15;
  int node0 = blockIdx.x * BN;
  int voff = 2 * L;                                  // short offset of this lane's dims

  // zero A tile: 32*1160 = 37120 shorts = 4640 b128 chunks over 512 threads
  {
    bf16x8 z = 0;
    #pragma unroll
    for (int i = 0; i < 9; ++i) ((bf16x8*)As)[i * 512 + t] = z;
    if (t < 32) ((bf16x8*)As)[9 * 512 + t] = z;
  }

  // hoist depth-4 B prefetch across the aggregation phase (same addrs every block: L2-hot)
  const uint16_t* wp = Wf + (size_t)w * 512 + (size_t)L * 8;
  bf16x8 b0 = *(const bf16x8*)(wp);
  bf16x8 b1 = *(const bf16x8*)(wp + 1 * 4096);
  bf16x8 b2 = *(const bf16x8*)(wp + 2 * 4096);
  bf16x8 b3 = *(const bf16x8*)(wp + 3 * 4096);

  __syncthreads();

  // ---- phase 1 ----
  // root slabs: wave w copies rows w*4..w*4+3 (coalesced, overlaps edge streaming)
  #pragma unroll
  for (int ni = 0; ni < 4; ++ni) {
    int r = w * 4 + ni;
    int n = node0 + r;
    if (n < N_NODES)
      *(uint32_t*)(As + (size_t)r * LDA + R_REL * HID + voff) =
          *(const uint32_t*)(hin + (size_t)n * HID + voff);
  }

  {
    int s0 = offs8[(size_t)node0 * R_REL];
    int s1 = offs8[(size_t)min(node0 + BN, N_NODES) * R_REL];
    int ce = s1 - s0;
    int e0 = s0 + ((ce * w) >> 3);
    int e1 = s0 + ((ce * (w + 1)) >> 3);
    uint32_t kskip = 0xFFFFFFFEu;
    if (e0 > s0) kskip = epack[e0 - 1] >> 16;        // uniform scalar load
    uint32_t cur = 0xFFFFFFFFu;
    float ax = 0.f, ay = 0.f; int ct = 0;
    bool done = false;
    int lsel = L & 15;
    uint32_t pv = (e0 < s1) ? epack[e0 + lsel] : 0u;
    #pragma unroll 1
    for (int g = e0; g < s1 && !done; g += 16) {
      uint32_t pc = pv;
      int m = min(16, s1 - g);
      pv = epack[g + 16 + lsel];                     // prefetch (buffer padded +64)
      uint32_t sv[16], vv[16];
      #pragma unroll
      for (int i = 0; i < 16; ++i) if (i < m) {
        uint32_t s = (uint32_t)__builtin_amdgcn_readlane((int)pc, i);   // SGPR
        sv[i] = s;
        vv[i] = *(const uint32_t*)(hin + (size_t)(s & 0xFFFFu) * HID + voff);
      }
      #pragma unroll
      for (int i = 0; i < 16; ++i) {
        if (i >= m) break;
        uint32_t k = sv[i] >> 16;                    // (loc<<3)|rel, scalar
        if (k == cur) {
          uint32_t v = vv[i];
          ax += bf2f(v & 0xFFFFu); ay += bf2f(v >> 16); ++ct;
        } else if (k != kskip) {
          if (cur != 0xFFFFFFFFu) {                  // flush finished group (scalar branch)
            float iv = __builtin_amdgcn_rcpf((float)ct);
            *(uint32_t*)(As + (size_t)(cur >> 3) * LDA + (cur & 7u) * HID + voff) =
                pack2bf(ax * iv, ay * iv);
          }
          if (g + i >= e1) { done = true; cur = 0xFFFFFFFFu; break; }  // next wave's group
          cur = k;
          uint32_t v = vv[i];
          ax = bf2f(v & 0xFFFFu); ay = bf2f(v >> 16); ct = 1;
        }
      }
    }
    if (cur != 0xFFFFFFFFu) {
      float iv = __builtin_amdgcn_rcpf((float)ct);
      *(uint32_t*)(As + (size_t)(cur >> 3) * LDA + (cur & 7u) * HID + voff) =
          pack2bf(ax * iv, ay * iv);
    }
  }
  __syncthreads();

  // ---- phase 2: GEMM. wave w: rows 0..32 (2 m-frags) x cols [w*16, w*16+16) ----
  f32x4 acc0 = (f32x4){0.f, 0.f, 0.f, 0.f};
  f32x4 acc1 = (f32x4){0.f, 0.f, 0.f, 0.f};
  const uint16_t* ap = As + l16 * LDA + quad * 8;   // A[m*16+l16][kc*32+quad*8+e]

  bf16x8 a0 = *(const bf16x8*)(ap);
  bf16x8 a1 = *(const bf16x8*)(ap + 16 * LDA);

  #pragma unroll 1
  for (int kc = 0; kc < 32; kc += 4) {
    bf16x8 n0, n1, nb;
    n0 = *(const bf16x8*)(ap + (kc + 1) * 32);
    n1 = *(const bf16x8*)(ap + (kc + 1) * 32 + 16 * LDA);
    nb = *(const bf16x8*)(wp + (size_t)(kc + 4) * 4096);
    acc0 = MFMA(a0, b0, acc0);
    acc1 = MFMA(a1, b0, acc1);
    a0 = n0; a1 = n1; b0 = nb;
    n0 = *(const bf16x8*)(ap + (kc + 2) * 32);
    n1 = *(const bf16x8*)(ap + (kc + 2) * 32 + 16 * LDA);
    nb = *(const bf16x8*)(wp + (size_t)(kc + 5) * 4096);
    acc0 = MFMA(a0, b1, acc0);
    acc1 = MFMA(a1, b1, acc1);
    a0 = n0; a1 = n1; b1 = nb;
    n0 = *(const bf16x8*)(ap + (kc + 3) * 32);
    n1 = *(const bf16x8*)(ap + (kc + 3) * 32 + 16 * LDA);
    nb = *(const bf16x8*)(wp + (size_t)(kc + 6) * 4096);
    acc0 = MFMA(a0, b2, acc0);
    acc1 = MFMA(a1, b2, acc1);
    a0 = n0; a1 = n1; b2 = nb;
    n0 = *(const bf16x8*)(ap + (kc + 4) * 32);
    n1 = *(const bf16x8*)(ap + (kc + 4) * 32 + 16 * LDA);
    nb = *(const bf16x8*)(wp + (size_t)(kc + 7) * 4096);
    acc0 = MFMA(a0, b3, acc0);
    acc1 = MFMA(a1, b3, acc1);
    a0 = n0; a1 = n1; b3 = nb;
  }
  {
    bf16x8 n0, n1;
    n0 = *(const bf16x8*)(ap + 33 * 32);
    n1 = *(const bf16x8*)(ap + 33 * 32 + 16 * LDA);
    acc0 = MFMA(a0, b0, acc0);
    acc1 = MFMA(a1, b0, acc1);
    a0 = n0; a1 = n1;
    n0 = *(const bf16x8*)(ap + 34 * 32);
    n1 = *(const bf16x8*)(ap + 34 * 32 + 16 * LDA);
    acc0 = MFMA(a0, b1, acc0);
    acc1 = MFMA(a1, b1, acc1);
    a0 = n0; a1 = n1;
    n0 = *(const bf16x8*)(ap + 35 * 32);
    n1 = *(const bf16x8*)(ap + 35 * 32 + 16 * LDA);
    acc0 = MFMA(a0, b2, acc0);
    acc1 = MFMA(a1, b2, acc1);
    a0 = n0; a1 = n1;
    acc0 = MFMA(a0, b3, acc0);
    acc1 = MFMA(a1, b3, acc1);
  }

  // ---- epilogue: C/D layout col=lane&15, row=quad*4+reg ----
  int col = w * 16 + l16;
  float bv = bias[col];
  if (MODE == 0) {
    #pragma unroll
    for (int rg = 0; rg < 4; ++rg) {
      int row = node0 + quad * 4 + rg;
      if (row < N_NODES)
        ((uint16_t*)hout)[(size_t)row * HID + col] = f2bf(fmaxf(acc0[rg] + bv, 0.f));
    }
    #pragma unroll
    for (int rg = 0; rg < 4; ++rg) {
      int row = node0 + 16 + quad * 4 + rg;
      if (row < N_NODES)
        ((uint16_t*)hout)[(size_t)row * HID + col] = f2bf(fmaxf(acc1[rg] + bv, 0.f));
    }
  } else {
    // fused global-mean-pool partials (sum; divide in k_final)
    bool fast = false;
    int gA = 0;
    if (node0 + BN <= N_NODES) {
      gA = batch[node0];
      int gB = batch[node0 + BN - 1];
      fast = (gA == gB);
    }
    if (fast) {
      float s = 0.f;
      #pragma unroll
      for (int rg = 0; rg < 4; ++rg) s += fmaxf(acc0[rg] + bv, 0.f);
      #pragma unroll
      for (int rg = 0; rg < 4; ++rg) s += fmaxf(acc1[rg] + bv, 0.f);
      s += __shfl_xor(s, 16);
      s += __shfl_xor(s, 32);
      if (quad == 0) atomicAdd(&psum[gA * HID + col], s);
    } else {
      int gp = -1; float run = 0.f;
      #pragma unroll
      for (int k = 0; k < 8; ++k) {
        int rg = k & 3;
        int row = node0 + (k >> 2) * 16 + quad * 4 + rg;
        float v = (k < 4) ? acc0[rg] : acc1[rg];
        if (row < N_NODES) {
          int gg = batch[row];
          if (gg != gp) {
            if (gp >= 0) atomicAdd(&psum[gp * HID + col], run);
            run = 0.f; gp = gg;
          }
          run += fmaxf(v + bv, 0.f);
        }
      }
      if (gp >= 0) atomicAdd(&psum[gp * HID + col], run);
    }
  }
}

__global__ __launch_bounds__(1024) void k_final(const float* __restrict__ psum,
                                                const int* __restrict__ gs, const int* __restrict__ ge,
                                                const float* __restrict__ linW, const float* __restrict__ linb,
                                                float* __restrict__ out) {
  __shared__ float lp[NUM_GRAPHS * HID];       // 32 KB
  __shared__ float lw[HID * NUM_CLASSES];      // 8 KB
  int i = threadIdx.x;
  #pragma unroll
  for (int j = 0; j < 8; ++j) lp[j * 1024 + i] = psum[j * 1024 + i];
  #pragma unroll
  for (int j = 0; j < 2; ++j) lw[j * 1024 + i] = linW[j * 1024 + i];
  __syncthreads();
  int g = i >> 4, c = i & 15;
  float inv = 1.f / fmaxf((float)(ge[g] - gs[g]), 1.f);
  float s = 0.f;
  #pragma unroll 8
  for (int k = 0; k < HID; ++k) s += lp[g * HID + k] * lw[k * NUM_CLASSES + c];
  out[i] = s * inv + linb[c];
}

// ---------- launch ----------
extern "C" void kernel_launch(void* const* d_in, const int* in_sizes, int n_in,
                              void* d_out, int out_size, void* d_ws, size_t ws_size,
                              hipStream_t stream) {
  const float* x     = (const float*)d_in[0];
  const int*   ei    = (const int*)d_in[1];   // [2,E]: [0..E) src, [E..2E) dst
  const int*   et    = (const int*)d_in[2];
  const int*   batch = (const int*)d_in[3];
  const float* W1    = (const float*)d_in[4];
  const float* root1 = (const float*)d_in[5];
  const float* b1    = (const float*)d_in[6];
  const float* W2    = (const float*)d_in[7];
  const float* root2 = (const float*)d_in[8];
  const float* b2    = (const float*)d_in[9];
  const float* linW  = (const float*)d_in[10];
  const float* linb  = (const float*)d_in[11];
  float* out = (float*)d_out;

  char* ws = (char*)d_ws;
  size_t off = 0;
  auto alloc = [&](size_t bytes) -> char* {
    char* p = ws + off;
    off += (bytes + 255) & ~(size_t)255;
    return p;
  };
  // zero-region: deg8 | gb | psum (contiguous, one memset)
  int*      deg8  = (int*)alloc((size_t)N8 * 4);
  int*      gb    = (int*)alloc(2 * NUM_GRAPHS * 4);
  float*    psum  = (float*)alloc((size_t)NUM_GRAPHS * HID * 4);
  size_t zbytes = (size_t)N8 * 4 + 512 + (size_t)NUM_GRAPHS * HID * 4;
  int*      gs    = gb;
  int*      ge    = gb + NUM_GRAPHS;
  int*      offs8 = (int*)alloc((size_t)(N8 + 1) * 4);
  int*      nxt   = (int*)alloc((size_t)N8 * 4);
  int*      bsum  = (int*)alloc(512 * 4);
  uint32_t* epack = (uint32_t*)alloc((size_t)(N_EDGES + 64) * 4);   // +64: prefetch overrun pad
  uint16_t* Wf1   = (uint16_t*)alloc((size_t)KOUT * KIN * 2);
  uint16_t* Wf2   = (uint16_t*)alloc((size_t)KOUT * KIN * 2);
  uint16_t* xb    = (uint16_t*)alloc((size_t)N_NODES * HID * 2);
  uint16_t* h1b   = (uint16_t*)alloc((size_t)N_NODES * HID * 2);

  hipMemsetAsync(deg8, 0, zbytes, stream);

  int nb = (N8 + 1023) / 1024;          // 391
  k_prep<<<HIST_B + BND_B + WP_B + CVT_B, 256, 0, stream>>>(
      ei, et, deg8, batch, gs, ge, W1, root1, Wf1, W2, root2, Wf2, x, xb);
  k_scan1<<<nb, 256, 0, stream>>>(deg8, offs8, bsum);
  k_scan2<<<1, 512, 0, stream>>>(bsum, nb);
  k_scan3<<<(N8 + 255) / 256, 256, 0, stream>>>(offs8, nxt, bsum);
  k_scatter<<<(N_EDGES + 255) / 256, 256, 0, stream>>>(ei, et, nxt, epack);

  // fused layers: sorted-stream aggregate -> As[32,1152] in LDS -> MFMA with Wcat
  k_fused<0><<<NBLK, 512, 0, stream>>>(xb,  epack, offs8, Wf1, b1, h1b, nullptr, nullptr);
  k_fused<1><<<NBLK, 512, 0, stream>>>(h1b, epack, offs8, Wf2, b2, nullptr, psum, batch);

  k_final<<<1, 1024, 0, stream>>>(psum, gs, ge, linW, linb, out);
}

// Round 6
// 282.094 us; speedup vs baseline: 3.6614x; 1.1086x over previous
//
#include <hip/hip_runtime.h>
#include <hip/hip_bf16.h>
#include <stdint.h>

#define N_NODES 50000
#define N_EDGES 500000
#define R_REL 8
#define HID 128
#define KIN 128              // input features per slab
#define KOUT 1152            // 9*128: concat K dim (W_0..W_7 | root)
#define N8 400000            // N_NODES * R_REL composite buckets
#define NUM_GRAPHS 64
#define NUM_CLASSES 16

#define BN 32                // dst-nodes per fused block
#define LDA 1160             // A row stride in shorts (2320 B)
#define NBLK 1563            // ceil(50000/32)

typedef __attribute__((ext_vector_type(8))) short bf16x8;
typedef __attribute__((ext_vector_type(4))) float f32x4;

// ---------- helpers ----------
__device__ __forceinline__ uint16_t f2bf(float f) {
  uint32_t u = __float_as_uint(f);
  u += 0x7FFFu + ((u >> 16) & 1u);   // RNE
  return (uint16_t)(u >> 16);
}
__device__ __forceinline__ float bf2f(uint32_t b) {
  return __uint_as_float(b << 16);
}
__device__ __forceinline__ uint32_t pack2bf(float a, float b) {
  return (uint32_t)f2bf(a) | ((uint32_t)f2bf(b) << 16);
}
#define MFMA(a, b, c) __builtin_amdgcn_mfma_f32_16x16x32_bf16((a), (b), (c), 0, 0, 0)

// ---------- merged prep: hist | bounds | weightprep (LDS-staged) | x->bf16 ----------
#define HIST_B 1954
#define BND_B 196
#define WP_B 72             // 2 matrices x 36 kc-chunks
#define CVT_B 3125          // N_NODES*HID/8 / 256
__global__ __launch_bounds__(256) void k_prep(const int* __restrict__ ei, const int* __restrict__ et,
                                              int* __restrict__ deg8,
                                              const int* __restrict__ batch,
                                              int* __restrict__ gs, int* __restrict__ ge,
                                              const float* __restrict__ W1, const float* __restrict__ root1,
                                              uint16_t* __restrict__ Wf1,
                                              const float* __restrict__ W2, const float* __restrict__ root2,
                                              uint16_t* __restrict__ Wf2,
                                              const float* __restrict__ x, uint16_t* __restrict__ xb) {
  int b = blockIdx.x;
  int t = threadIdx.x;
  if (b < HIST_B) {                                 // (dst,rel) edge histogram (400K buckets)
    int i = b * 256 + t;
    if (i < N_EDGES) atomicAdd(&deg8[ei[N_EDGES + i] * R_REL + et[i]], 1);
    return;
  }
  b -= HIST_B;
  if (b < BND_B) {                                  // graph boundaries (batch sorted)
    int i = b * 256 + t;
    if (i < N_NODES) {
      int g = batch[i];
      if (i == 0) gs[g] = 0;
      else { int pg = batch[i - 1]; if (pg != g) { ge[pg] = i; gs[g] = i; } }
      if (i == N_NODES - 1) ge[g] = N_NODES;
    }
    return;
  }
  b -= BND_B;
  if (b < WP_B) {
    // weight prep, LDS-staged: block handles one kc-chunk (32 K-rows x 128 cols) of one matrix.
    __shared__ float lw[32 * 129];
    const float* W    = (b < 36) ? W1 : W2;
    const float* root = (b < 36) ? root1 : root2;
    uint16_t*    Wf   = (b < 36) ? Wf1 : Wf2;
    int kc = (b < 36) ? b : b - 36;
    #pragma unroll
    for (int j = 0; j < 4; ++j) {
      int fi = j * 256 + t;                  // float4 slot over 32 rows x 32 f4
      int row = fi >> 5, c4 = fi & 31;
      int kk = kc * 32 + row;
      int s = kk >> 7, k = kk & 127;
      const float* src = (s < R_REL) ? (W + ((size_t)s * KIN + k) * HID) : (root + (size_t)k * HID);
      float4 v = *(const float4*)(src + c4 * 4);
      lw[row * 129 + c4 * 4 + 0] = v.x;
      lw[row * 129 + c4 * 4 + 1] = v.y;
      lw[row * 129 + c4 * 4 + 2] = v.z;
      lw[row * 129 + c4 * 4 + 3] = v.w;
    }
    __syncthreads();
    #pragma unroll
    for (int p = 0; p < 2; ++p) {
      int slot = p * 256 + t;                // 8 frags x 64 lanes
      int nt = slot >> 6, L = slot & 63;
      int quad = L >> 4, l16 = L & 15;
      uint16_t tmp[8];
      #pragma unroll
      for (int e = 0; e < 8; ++e)
        tmp[e] = f2bf(lw[(quad * 8 + e) * 129 + nt * 16 + l16]);
      uint4 o;
      o.x = (uint32_t)tmp[0] | ((uint32_t)tmp[1] << 16);
      o.y = (uint32_t)tmp[2] | ((uint32_t)tmp[3] << 16);
      o.z = (uint32_t)tmp[4] | ((uint32_t)tmp[5] << 16);
      o.w = (uint32_t)tmp[6] | ((uint32_t)tmp[7] << 16);
      *(uint4*)(Wf + ((size_t)(kc * 8 + nt) * 512 + (size_t)L * 8)) = o;
    }
    return;
  }
  b -= WP_B;
  {                                                 // x (fp32) -> xb (bf16), 8 elems/thread
    int i = b * 256 + t;                            // < 800000 exact
    const float4* p = (const float4*)x + (size_t)i * 2;
    float4 a = p[0], c = p[1];
    uint4 o;
    o.x = pack2bf(a.x, a.y); o.y = pack2bf(a.z, a.w);
    o.z = pack2bf(c.x, c.y); o.w = pack2bf(c.z, c.w);
    *(uint4*)(xb + (size_t)i * 8) = o;
  }
}

// ---------- scans over 400K (dst,rel) buckets ----------
__global__ __launch_bounds__(256) void k_scan1(const int* __restrict__ deg8, int* __restrict__ offs8,
                                               int* __restrict__ bsum) {
  __shared__ int sh[256];
  int t = threadIdx.x;
  int base = blockIdx.x * 1024 + t * 4;
  int v[4]; int s = 0;
  #pragma unroll
  for (int i = 0; i < 4; ++i) { int idx = base + i; v[i] = (idx < N8) ? deg8[idx] : 0; s += v[i]; }
  sh[t] = s;
  __syncthreads();
  for (int d = 1; d < 256; d <<= 1) {
    int add = (t >= d) ? sh[t - d] : 0;
    __syncthreads();
    sh[t] += add;
    __syncthreads();
  }
  int run = sh[t] - s;
  if (t == 255) bsum[blockIdx.x] = sh[255];
  #pragma unroll
  for (int i = 0; i < 4; ++i) { int idx = base + i; if (idx < N8) offs8[idx] = run; run += v[i]; }
}

__global__ __launch_bounds__(512) void k_scan2(int* __restrict__ bsum, int nb) {
  __shared__ int sh[512];
  int t = threadIdx.x;
  int v = (t < nb) ? bsum[t] : 0;
  sh[t] = v;
  __syncthreads();
  for (int d = 1; d < 512; d <<= 1) {
    int add = (t >= d) ? sh[t - d] : 0;
    __syncthreads();
    sh[t] += add;
    __syncthreads();
  }
  if (t < nb) bsum[t] = sh[t] - v;   // exclusive
}

__global__ __launch_bounds__(256) void k_scan3(int* __restrict__ offs8, int* __restrict__ nxt,
                                               const int* __restrict__ bsum) {
  int i = blockIdx.x * 256 + threadIdx.x;
  if (i < N8) {
    int o = offs8[i] + bsum[i >> 10];
    offs8[i] = o;
    nxt[i] = o;
  }
  if (i == 0) offs8[N8] = N_EDGES;
}

// scatter into (dst,rel) buckets: stream becomes sorted by (dst,rel).
// epack = src | rel<<16 | (dst&31)<<19  (key = epack>>16 unique per group within a block)
__global__ __launch_bounds__(256) void k_scatter(const int* __restrict__ ei, const int* __restrict__ et,
                                                 int* __restrict__ nxt, uint32_t* __restrict__ epack) {
  int i = blockIdx.x * 256 + threadIdx.x;
  if (i < N_EDGES) {
    int rel = et[i];
    int dst = ei[N_EDGES + i];
    int p = atomicAdd(&nxt[dst * R_REL + rel], 1);
    epack[p] = (uint32_t)ei[i] | ((uint32_t)rel << 16) | ((uint32_t)(dst & 31) << 19);
  }
}

// ---------- fused layer: sorted-stream aggregate -> MFMA transform ----------
// Block = 32 dst nodes, 512 threads (8 waves), LDS As[32][1160] bf16 (74240 B, 2 blocks/CU).
// Phase 1: waves cooperatively stream the block's edge range in flat chunks. Stream is
//   (dst,rel)-sorted; a wave owns every group whose FIRST edge lies in its chunk.
//   KEY CHANGE vs round 4: the 16-deep extract+gather batch is BRANCH-FREE (clamped
//   instead of guarded) so the compiler keeps all 16 loads in flight (VGPR ~100, not 52).
//   Guards remain only in the (scalar-branch) accumulate section.
// Phase 2: out[32,128] = As[32,1152] @ Wcat; wave w owns cols [w*16,w*16+16); depth-4 B prefetch.
// MODE 0: write bf16 hout. MODE 1: fused global-mean-pool partials into psum.
template<int MODE>
__global__ __launch_bounds__(512, 4) void k_fused(const uint16_t* __restrict__ hin,
                                                  const uint32_t* __restrict__ epack,
                                                  const int* __restrict__ offs8,
                                                  const uint16_t* __restrict__ Wf,
                                                  const float* __restrict__ bias,
                                                  void* __restrict__ hout,
                                                  float* __restrict__ psum,
                                                  const int* __restrict__ batch) {
  __shared__ __align__(16) uint16_t As[BN * LDA];
  int t = threadIdx.x;
  int w = __builtin_amdgcn_readfirstlane(t >> 6);
  int L = t & 63;
  int quad = L >> 4, l16 = L & 15;
  int node0 = blockIdx.x * BN;
  int voff = 2 * L;                                  // short offset of this lane's dims

  // zero A tile: 32*1160 = 37120 shorts = 4640 b128 chunks over 512 threads
  {
    bf16x8 z = 0;
    #pragma unroll
    for (int i = 0; i < 9; ++i) ((bf16x8*)As)[i * 512 + t] = z;
    if (t < 32) ((bf16x8*)As)[9 * 512 + t] = z;
  }

  // hoist depth-4 B prefetch across the aggregation phase (same addrs every block: L2-hot)
  const uint16_t* wp = Wf + (size_t)w * 512 + (size_t)L * 8;
  bf16x8 b0 = *(const bf16x8*)(wp);
  bf16x8 b1 = *(const bf16x8*)(wp + 1 * 4096);
  bf16x8 b2 = *(const bf16x8*)(wp + 2 * 4096);
  bf16x8 b3 = *(const bf16x8*)(wp + 3 * 4096);

  __syncthreads();

  // ---- phase 1 ----
  // root slabs: wave w copies rows w*4..w*4+3 (coalesced, overlaps edge streaming)
  #pragma unroll
  for (int ni = 0; ni < 4; ++ni) {
    int r = w * 4 + ni;
    int n = node0 + r;
    if (n < N_NODES)
      *(uint32_t*)(As + (size_t)r * LDA + R_REL * HID + voff) =
          *(const uint32_t*)(hin + (size_t)n * HID + voff);
  }

  {
    int s0 = offs8[(size_t)node0 * R_REL];
    int s1 = offs8[(size_t)min(node0 + BN, N_NODES) * R_REL];
    int ce = s1 - s0;
    int e0 = s0 + ((ce * w) >> 3);
    int e1 = s0 + ((ce * (w + 1)) >> 3);
    uint32_t kskip = 0xFFFFFFFEu;
    if (e0 > s0) kskip = epack[e0 - 1] >> 16;        // uniform scalar load
    uint32_t cur = 0xFFFFFFFFu;
    float ax = 0.f, ay = 0.f; int ct = 0;
    bool done = false;
    int lsel = L & 15;
    uint32_t pv = epack[e0 + lsel];                  // pad covers overrun
    #pragma unroll 1
    for (int g = e0; g < s1 && !done; g += 16) {
      uint32_t pc = pv;
      int m = min(16, s1 - g);
      pv = epack[g + 16 + lsel];                     // prefetch (buffer padded +64)
      uint32_t sv[16], vv[16];
      // branch-free extraction: all 16 readlanes unconditional
      #pragma unroll
      for (int i = 0; i < 16; ++i)
        sv[i] = (uint32_t)__builtin_amdgcn_readlane((int)pc, i);   // SGPR
      // branch-free gathers: clamp src so tail-garbage stays in-bounds; all 16 issued together
      #pragma unroll
      for (int i = 0; i < 16; ++i) {
        uint32_t src = sv[i] & 0xFFFFu;
        src = (src < (uint32_t)N_NODES) ? src : 0u;                // scalar select
        vv[i] = *(const uint32_t*)(hin + (size_t)src * HID + voff);
      }
      // accumulate: guards here are scalar branches (m, keys all in SGPRs)
      #pragma unroll
      for (int i = 0; i < 16; ++i) {
        if (i >= m) break;
        uint32_t k = sv[i] >> 16;                    // (loc<<3)|rel, scalar
        if (k == cur) {
          uint32_t v = vv[i];
          ax += bf2f(v & 0xFFFFu); ay += bf2f(v >> 16); ++ct;
        } else if (k != kskip) {
          if (cur != 0xFFFFFFFFu) {                  // flush finished group (scalar branch)
            float iv = __builtin_amdgcn_rcpf((float)ct);
            *(uint32_t*)(As + (size_t)(cur >> 3) * LDA + (cur & 7u) * HID + voff) =
                pack2bf(ax * iv, ay * iv);
          }
          if (g + i >= e1) { done = true; cur = 0xFFFFFFFFu; break; }  // next wave's group
          cur = k;
          uint32_t v = vv[i];
          ax = bf2f(v & 0xFFFFu); ay = bf2f(v >> 16); ct = 1;
        }
      }
    }
    if (cur != 0xFFFFFFFFu) {
      float iv = __builtin_amdgcn_rcpf((float)ct);
      *(uint32_t*)(As + (size_t)(cur >> 3) * LDA + (cur & 7u) * HID + voff) =
          pack2bf(ax * iv, ay * iv);
    }
  }
  __syncthreads();

  // ---- phase 2: GEMM. wave w: rows 0..32 (2 m-frags) x cols [w*16, w*16+16) ----
  f32x4 acc0 = (f32x4){0.f, 0.f, 0.f, 0.f};
  f32x4 acc1 = (f32x4){0.f, 0.f, 0.f, 0.f};
  const uint16_t* ap = As + l16 * LDA + quad * 8;   // A[m*16+l16][kc*32+quad*8+e]

  bf16x8 a0 = *(const bf16x8*)(ap);
  bf16x8 a1 = *(const bf16x8*)(ap + 16 * LDA);

  #pragma unroll 1
  for (int kc = 0; kc < 32; kc += 4) {
    bf16x8 n0, n1, nb;
    n0 = *(const bf16x8*)(ap + (kc + 1) * 32);
    n1 = *(const bf16x8*)(ap + (kc + 1) * 32 + 16 * LDA);
    nb = *(const bf16x8*)(wp + (size_t)(kc + 4) * 4096);
    acc0 = MFMA(a0, b0, acc0);
    acc1 = MFMA(a1, b0, acc1);
    a0 = n0; a1 = n1; b0 = nb;
    n0 = *(const bf16x8*)(ap + (kc + 2) * 32);
    n1 = *(const bf16x8*)(ap + (kc + 2) * 32 + 16 * LDA);
    nb = *(const bf16x8*)(wp + (size_t)(kc + 5) * 4096);
    acc0 = MFMA(a0, b1, acc0);
    acc1 = MFMA(a1, b1, acc1);
    a0 = n0; a1 = n1; b1 = nb;
    n0 = *(const bf16x8*)(ap + (kc + 3) * 32);
    n1 = *(const bf16x8*)(ap + (kc + 3) * 32 + 16 * LDA);
    nb = *(const bf16x8*)(wp + (size_t)(kc + 6) * 4096);
    acc0 = MFMA(a0, b2, acc0);
    acc1 = MFMA(a1, b2, acc1);
    a0 = n0; a1 = n1; b2 = nb;
    n0 = *(const bf16x8*)(ap + (kc + 4) * 32);
    n1 = *(const bf16x8*)(ap + (kc + 4) * 32 + 16 * LDA);
    nb = *(const bf16x8*)(wp + (size_t)(kc + 7) * 4096);
    acc0 = MFMA(a0, b3, acc0);
    acc1 = MFMA(a1, b3, acc1);
    a0 = n0; a1 = n1; b3 = nb;
  }
  {
    bf16x8 n0, n1;
    n0 = *(const bf16x8*)(ap + 33 * 32);
    n1 = *(const bf16x8*)(ap + 33 * 32 + 16 * LDA);
    acc0 = MFMA(a0, b0, acc0);
    acc1 = MFMA(a1, b0, acc1);
    a0 = n0; a1 = n1;
    n0 = *(const bf16x8*)(ap + 34 * 32);
    n1 = *(const bf16x8*)(ap + 34 * 32 + 16 * LDA);
    acc0 = MFMA(a0, b1, acc0);
    acc1 = MFMA(a1, b1, acc1);
    a0 = n0; a1 = n1;
    n0 = *(const bf16x8*)(ap + 35 * 32);
    n1 = *(const bf16x8*)(ap + 35 * 32 + 16 * LDA);
    acc0 = MFMA(a0, b2, acc0);
    acc1 = MFMA(a1, b2, acc1);
    a0 = n0; a1 = n1;
    acc0 = MFMA(a0, b3, acc0);
    acc1 = MFMA(a1, b3, acc1);
  }

  // ---- epilogue: C/D layout col=lane&15, row=quad*4+reg ----
  int col = w * 16 + l16;
  float bv = bias[col];
  if (MODE == 0) {
    #pragma unroll
    for (int rg = 0; rg < 4; ++rg) {
      int row = node0 + quad * 4 + rg;
      if (row < N_NODES)
        ((uint16_t*)hout)[(size_t)row * HID + col] = f2bf(fmaxf(acc0[rg] + bv, 0.f));
    }
    #pragma unroll
    for (int rg = 0; rg < 4; ++rg) {
      int row = node0 + 16 + quad * 4 + rg;
      if (row < N_NODES)
        ((uint16_t*)hout)[(size_t)row * HID + col] = f2bf(fmaxf(acc1[rg] + bv, 0.f));
    }
  } else {
    // fused global-mean-pool partials (sum; divide in k_final)
    bool fast = false;
    int gA = 0;
    if (node0 + BN <= N_NODES) {
      gA = batch[node0];
      int gB = batch[node0 + BN - 1];
      fast = (gA == gB);
    }
    if (fast) {
      float s = 0.f;
      #pragma unroll
      for (int rg = 0; rg < 4; ++rg) s += fmaxf(acc0[rg] + bv, 0.f);
      #pragma unroll
      for (int rg = 0; rg < 4; ++rg) s += fmaxf(acc1[rg] + bv, 0.f);
      s += __shfl_xor(s, 16);
      s += __shfl_xor(s, 32);
      if (quad == 0) atomicAdd(&psum[gA * HID + col], s);
    } else {
      int gp = -1; float run = 0.f;
      #pragma unroll
      for (int k = 0; k < 8; ++k) {
        int rg = k & 3;
        int row = node0 + (k >> 2) * 16 + quad * 4 + rg;
        float v = (k < 4) ? acc0[rg] : acc1[rg];
        if (row < N_NODES) {
          int gg = batch[row];
          if (gg != gp) {
            if (gp >= 0) atomicAdd(&psum[gp * HID + col], run);
            run = 0.f; gp = gg;
          }
          run += fmaxf(v + bv, 0.f);
        }
      }
      if (gp >= 0) atomicAdd(&psum[gp * HID + col], run);
    }
  }
}

__global__ __launch_bounds__(1024) void k_final(const float* __restrict__ psum,
                                                const int* __restrict__ gs, const int* __restrict__ ge,
                                                const float* __restrict__ linW, const float* __restrict__ linb,
                                                float* __restrict__ out) {
  __shared__ float lp[NUM_GRAPHS * HID];       // 32 KB
  __shared__ float lw[HID * NUM_CLASSES];      // 8 KB
  int i = threadIdx.x;
  #pragma unroll
  for (int j = 0; j < 8; ++j) lp[j * 1024 + i] = psum[j * 1024 + i];
  #pragma unroll
  for (int j = 0; j < 2; ++j) lw[j * 1024 + i] = linW[j * 1024 + i];
  __syncthreads();
  int g = i >> 4, c = i & 15;
  float inv = 1.f / fmaxf((float)(ge[g] - gs[g]), 1.f);
  float s = 0.f;
  #pragma unroll 8
  for (int k = 0; k < HID; ++k) s += lp[g * HID + k] * lw[k * NUM_CLASSES + c];
  out[i] = s * inv + linb[c];
}

// ---------- launch ----------
extern "C" void kernel_launch(void* const* d_in, const int* in_sizes, int n_in,
                              void* d_out, int out_size, void* d_ws, size_t ws_size,
                              hipStream_t stream) {
  const float* x     = (const float*)d_in[0];
  const int*   ei    = (const int*)d_in[1];   // [2,E]: [0..E) src, [E..2E) dst
  const int*   et    = (const int*)d_in[2];
  const int*   batch = (const int*)d_in[3];
  const float* W1    = (const float*)d_in[4];
  const float* root1 = (const float*)d_in[5];
  const float* b1    = (const float*)d_in[6];
  const float* W2    = (const float*)d_in[7];
  const float* root2 = (const float*)d_in[8];
  const float* b2    = (const float*)d_in[9];
  const float* linW  = (const float*)d_in[10];
  const float* linb  = (const float*)d_in[11];
  float* out = (float*)d_out;

  char* ws = (char*)d_ws;
  size_t off = 0;
  auto alloc = [&](size_t bytes) -> char* {
    char* p = ws + off;
    off += (bytes + 255) & ~(size_t)255;
    return p;
  };
  // zero-region: deg8 | gb | psum (contiguous, one memset)
  int*      deg8  = (int*)alloc((size_t)N8 * 4);
  int*      gb    = (int*)alloc(2 * NUM_GRAPHS * 4);
  float*    psum  = (float*)alloc((size_t)NUM_GRAPHS * HID * 4);
  size_t zbytes = (size_t)N8 * 4 + 512 + (size_t)NUM_GRAPHS * HID * 4;
  int*      gs    = gb;
  int*      ge    = gb + NUM_GRAPHS;
  int*      offs8 = (int*)alloc((size_t)(N8 + 1) * 4);
  int*      nxt   = (int*)alloc((size_t)N8 * 4);
  int*      bsum  = (int*)alloc(512 * 4);
  uint32_t* epack = (uint32_t*)alloc((size_t)(N_EDGES + 64) * 4);   // +64: prefetch overrun pad
  uint16_t* Wf1   = (uint16_t*)alloc((size_t)KOUT * KIN * 2);
  uint16_t* Wf2   = (uint16_t*)alloc((size_t)KOUT * KIN * 2);
  uint16_t* xb    = (uint16_t*)alloc((size_t)N_NODES * HID * 2);
  uint16_t* h1b   = (uint16_t*)alloc((size_t)N_NODES * HID * 2);

  hipMemsetAsync(deg8, 0, zbytes, stream);

  int nb = (N8 + 1023) / 1024;          // 391
  k_prep<<<HIST_B + BND_B + WP_B + CVT_B, 256, 0, stream>>>(
      ei, et, deg8, batch, gs, ge, W1, root1, Wf1, W2, root2, Wf2, x, xb);
  k_scan1<<<nb, 256, 0, stream>>>(deg8, offs8, bsum);
  k_scan2<<<1, 512, 0, stream>>>(bsum, nb);
  k_scan3<<<(N8 + 255) / 256, 256, 0, stream>>>(offs8, nxt, bsum);
  k_scatter<<<(N_EDGES + 255) / 256, 256, 0, stream>>>(ei, et, nxt, epack);

  // fused layers: sorted-stream aggregate -> As[32,1152] in LDS -> MFMA with Wcat
  k_fused<0><<<NBLK, 512, 0, stream>>>(xb,  epack, offs8, Wf1, b1, h1b, nullptr, nullptr);
  k_fused<1><<<NBLK, 512, 0, stream>>>(h1b, epack, offs8, Wf2, b2, nullptr, psum, batch);

  k_final<<<1, 1024, 0, stream>>>(psum, gs, ge, linW, linb, out);
}

// Round 8
// 267.684 us; speedup vs baseline: 3.8585x; 1.0538x over previous
//
#include <hip/hip_runtime.h>
#include <hip/hip_bf16.h>
#include <stdint.h>

#define N_NODES 50000
#define N_EDGES 500000
#define R_REL 8
#define HID 128
#define KIN 128              // input features per slab
#define KOUT 1152            // 9*128: concat K dim (W_0..W_7 | root)
#define N8 400000            // N_NODES * R_REL composite buckets
#define NUM_GRAPHS 64
#define NUM_CLASSES 16

#define BN 32                // dst-nodes per fused block
#define LDA 1160             // A row stride in shorts (2320 B)
#define NBLK 1563            // ceil(50000/32)

typedef __attribute__((ext_vector_type(8))) short bf16x8;
typedef __attribute__((ext_vector_type(4))) float f32x4;

// ---------- helpers ----------
__device__ __forceinline__ uint16_t f2bf(float f) {
  uint32_t u = __float_as_uint(f);
  u += 0x7FFFu + ((u >> 16) & 1u);   // RNE
  return (uint16_t)(u >> 16);
}
__device__ __forceinline__ float bf2f(uint32_t b) {
  return __uint_as_float(b << 16);
}
__device__ __forceinline__ uint32_t pack2bf(float a, float b) {
  return (uint32_t)f2bf(a) | ((uint32_t)f2bf(b) << 16);
}
#define MFMA(a, b, c) __builtin_amdgcn_mfma_f32_16x16x32_bf16((a), (b), (c), 0, 0, 0)

// ---------- merged prep: hist | bounds | weightprep (LDS-staged) | x->bf16 ----------
#define HIST_B 1954
#define BND_B 196
#define WP_B 72             // 2 matrices x 36 kc-chunks
#define CVT_B 3125          // N_NODES*HID/8 / 256
__global__ __launch_bounds__(256) void k_prep(const int* __restrict__ ei, const int* __restrict__ et,
                                              int* __restrict__ deg8,
                                              const int* __restrict__ batch,
                                              int* __restrict__ gs, int* __restrict__ ge,
                                              const float* __restrict__ W1, const float* __restrict__ root1,
                                              uint16_t* __restrict__ Wf1,
                                              const float* __restrict__ W2, const float* __restrict__ root2,
                                              uint16_t* __restrict__ Wf2,
                                              const float* __restrict__ x, uint16_t* __restrict__ xb) {
  int b = blockIdx.x;
  int t = threadIdx.x;
  if (b < HIST_B) {                                 // (dst,rel) edge histogram (400K buckets)
    int i = b * 256 + t;
    if (i < N_EDGES) atomicAdd(&deg8[ei[N_EDGES + i] * R_REL + et[i]], 1);
    return;
  }
  b -= HIST_B;
  if (b < BND_B) {                                  // graph boundaries (batch sorted)
    int i = b * 256 + t;
    if (i < N_NODES) {
      int g = batch[i];
      if (i == 0) gs[g] = 0;
      else { int pg = batch[i - 1]; if (pg != g) { ge[pg] = i; gs[g] = i; } }
      if (i == N_NODES - 1) ge[g] = N_NODES;
    }
    return;
  }
  b -= BND_B;
  if (b < WP_B) {
    // weight prep, LDS-staged: block handles one kc-chunk (32 K-rows x 128 cols) of one matrix.
    __shared__ float lw[32 * 129];
    const float* W    = (b < 36) ? W1 : W2;
    const float* root = (b < 36) ? root1 : root2;
    uint16_t*    Wf   = (b < 36) ? Wf1 : Wf2;
    int kc = (b < 36) ? b : b - 36;
    #pragma unroll
    for (int j = 0; j < 4; ++j) {
      int fi = j * 256 + t;                  // float4 slot over 32 rows x 32 f4
      int row = fi >> 5, c4 = fi & 31;
      int kk = kc * 32 + row;
      int s = kk >> 7, k = kk & 127;
      const float* src = (s < R_REL) ? (W + ((size_t)s * KIN + k) * HID) : (root + (size_t)k * HID);
      float4 v = *(const float4*)(src + c4 * 4);
      lw[row * 129 + c4 * 4 + 0] = v.x;
      lw[row * 129 + c4 * 4 + 1] = v.y;
      lw[row * 129 + c4 * 4 + 2] = v.z;
      lw[row * 129 + c4 * 4 + 3] = v.w;
    }
    __syncthreads();
    #pragma unroll
    for (int p = 0; p < 2; ++p) {
      int slot = p * 256 + t;                // 8 frags x 64 lanes
      int nt = slot >> 6, L = slot & 63;
      int quad = L >> 4, l16 = L & 15;
      uint16_t tmp[8];
      #pragma unroll
      for (int e = 0; e < 8; ++e)
        tmp[e] = f2bf(lw[(quad * 8 + e) * 129 + nt * 16 + l16]);
      uint4 o;
      o.x = (uint32_t)tmp[0] | ((uint32_t)tmp[1] << 16);
      o.y = (uint32_t)tmp[2] | ((uint32_t)tmp[3] << 16);
      o.z = (uint32_t)tmp[4] | ((uint32_t)tmp[5] << 16);
      o.w = (uint32_t)tmp[6] | ((uint32_t)tmp[7] << 16);
      *(uint4*)(Wf + ((size_t)(kc * 8 + nt) * 512 + (size_t)L * 8)) = o;
    }
    return;
  }
  b -= WP_B;
  {                                                 // x (fp32) -> xb (bf16), 8 elems/thread
    int i = b * 256 + t;                            // < 800000 exact
    const float4* p = (const float4*)x + (size_t)i * 2;
    float4 a = p[0], c = p[1];
    uint4 o;
    o.x = pack2bf(a.x, a.y); o.y = pack2bf(a.z, a.w);
    o.z = pack2bf(c.x, c.y); o.w = pack2bf(c.z, c.w);
    *(uint4*)(xb + (size_t)i * 8) = o;
  }
}

// ---------- scans over 400K (dst,rel) buckets ----------
__global__ __launch_bounds__(256) void k_scan1(const int* __restrict__ deg8, int* __restrict__ offs8,
                                               int* __restrict__ bsum) {
  __shared__ int sh[256];
  int t = threadIdx.x;
  int base = blockIdx.x * 1024 + t * 4;
  int v[4]; int s = 0;
  #pragma unroll
  for (int i = 0; i < 4; ++i) { int idx = base + i; v[i] = (idx < N8) ? deg8[idx] : 0; s += v[i]; }
  sh[t] = s;
  __syncthreads();
  for (int d = 1; d < 256; d <<= 1) {
    int add = (t >= d) ? sh[t - d] : 0;
    __syncthreads();
    sh[t] += add;
    __syncthreads();
  }
  int run = sh[t] - s;
  if (t == 255) bsum[blockIdx.x] = sh[255];
  #pragma unroll
  for (int i = 0; i < 4; ++i) { int idx = base + i; if (idx < N8) offs8[idx] = run; run += v[i]; }
}

// merged scan2+scan3: each 256-block covers i in [b*256,b*256+256) -> one 1024-chunk (b>>2);
// it re-derives the bsum prefix for that chunk itself (<=391 ints, trivial) -- one less launch.
__global__ __launch_bounds__(256) void k_scan23(int* __restrict__ offs8, int* __restrict__ nxt,
                                                const int* __restrict__ bsum, int nb) {
  __shared__ int red[4];
  int t = threadIdx.x;
  int blk = blockIdx.x >> 2;            // which 1024-chunk this block belongs to
  int pre = 0;
  for (int j = t; j < blk; j += 256) pre += bsum[j];
  #pragma unroll
  for (int d = 1; d < 64; d <<= 1) pre += __shfl_xor(pre, d);
  if ((t & 63) == 0) red[t >> 6] = pre;
  __syncthreads();
  int total = red[0] + red[1] + red[2] + red[3];
  int i = blockIdx.x * 256 + t;
  if (i < N8) {
    int o = offs8[i] + total;
    offs8[i] = o;
    nxt[i] = o;
  }
  if (i == 0) offs8[N8] = N_EDGES;
}

// scatter into (dst,rel) buckets: stream becomes sorted by (dst,rel).
// epack = src | rel<<16 | (dst&31)<<19  (key = epack>>16 unique per group within a block)
__global__ __launch_bounds__(256) void k_scatter(const int* __restrict__ ei, const int* __restrict__ et,
                                                 int* __restrict__ nxt, uint32_t* __restrict__ epack) {
  int i = blockIdx.x * 256 + threadIdx.x;
  if (i < N_EDGES) {
    int rel = et[i];
    int dst = ei[N_EDGES + i];
    int p = atomicAdd(&nxt[dst * R_REL + rel], 1);
    epack[p] = (uint32_t)ei[i] | ((uint32_t)rel << 16) | ((uint32_t)(dst & 31) << 19);
  }
}

// ---------- fused layer: sorted-stream aggregate -> split-K MFMA transform ----------
// Block = 32 dst nodes, 1024 threads (16 waves), LDS As[32][1160] bf16 (74240 B).
// Target 2 blocks/CU x 16 waves = 32 waves/CU (VGPR usage ~52 <= 64 as measured r5/r6;
// launch_bounds(1024,4) leaves the allocator a 128 budget rather than forcing 64).
// Phase 1: 16 waves cooperatively stream the block's (dst,rel)-sorted edge range in flat
//   chunks; branch-free 16-deep readlane+gather batches; a wave owns every group whose
//   first edge lies in its chunk; scalar-branch flush (bf16 ds_write with 1/cnt mean).
// Phase 2: split-K GEMM: wave = (nt = w&7, kh = w>>3); 18 kc each, depth-2 B prefetch;
//   kh-halves reduced through the As region reused as scratch (dead after A-reads).
// MODE 0: write bf16 hout. MODE 1: fused global-mean-pool partials into psum.
template<int MODE>
__global__ __launch_bounds__(1024, 4) void k_fused(const uint16_t* __restrict__ hin,
                                                   const uint32_t* __restrict__ epack,
                                                   const int* __restrict__ offs8,
                                                   const uint16_t* __restrict__ Wf,
                                                   const float* __restrict__ bias,
                                                   void* __restrict__ hout,
                                                   float* __restrict__ psum,
                                                   const int* __restrict__ batch) {
  __shared__ __align__(16) uint16_t As[BN * LDA];
  int t = threadIdx.x;
  int w = __builtin_amdgcn_readfirstlane(t >> 6);    // 0..15
  int L = t & 63;
  int quad = L >> 4, l16 = L & 15;
  int node0 = blockIdx.x * BN;
  int voff = 2 * L;                                  // short offset of this lane's dims
  int nt = w & 7, kh = w >> 3;

  // zero A tile: 32*1160 = 37120 shorts = 4640 b128 chunks over 1024 threads
  {
    bf16x8 z = 0;
    #pragma unroll
    for (int i = 0; i < 4; ++i) ((bf16x8*)As)[i * 1024 + t] = z;
    if (t < 544) ((bf16x8*)As)[4 * 1024 + t] = z;
  }

  // hoist depth-2 B prefetch across the aggregation phase (same addrs every block: L2-hot)
  const uint16_t* wpk = Wf + ((size_t)(kh * 18 * 8 + nt)) * 512 + (size_t)L * 8;
  bf16x8 b0 = *(const bf16x8*)(wpk);
  bf16x8 b1 = *(const bf16x8*)(wpk + 4096);

  __syncthreads();

  // ---- phase 1 ----
  // root slabs: wave w copies rows w*2..w*2+1 (coalesced, overlaps edge streaming)
  #pragma unroll
  for (int ni = 0; ni < 2; ++ni) {
    int r = w * 2 + ni;
    int n = node0 + r;
    if (n < N_NODES)
      *(uint32_t*)(As + (size_t)r * LDA + R_REL * HID + voff) =
          *(const uint32_t*)(hin + (size_t)n * HID + voff);
  }

  {
    int s0 = offs8[(size_t)node0 * R_REL];
    int s1 = offs8[(size_t)min(node0 + BN, N_NODES) * R_REL];
    int ce = s1 - s0;
    int e0 = s0 + ((ce * w) >> 4);
    int e1 = s0 + ((ce * (w + 1)) >> 4);
    uint32_t kskip = 0xFFFFFFFEu;
    if (e0 > s0) kskip = epack[e0 - 1] >> 16;        // uniform scalar load
    uint32_t cur = 0xFFFFFFFFu;
    float ax = 0.f, ay = 0.f; int ct = 0;
    bool done = false;
    int lsel = L & 15;
    uint32_t pv = epack[e0 + lsel];                  // pad covers overrun
    #pragma unroll 1
    for (int g = e0; g < s1 && !done; g += 16) {
      uint32_t pc = pv;
      int m = min(16, s1 - g);
      pv = epack[g + 16 + lsel];                     // prefetch (buffer padded +64)
      uint32_t sv[16], vv[16];
      // branch-free extraction: all 16 readlanes unconditional
      #pragma unroll
      for (int i = 0; i < 16; ++i)
        sv[i] = (uint32_t)__builtin_amdgcn_readlane((int)pc, i);   // SGPR
      // branch-free gathers: clamp src so tail-garbage stays in-bounds; all 16 in flight
      #pragma unroll
      for (int i = 0; i < 16; ++i) {
        uint32_t src = sv[i] & 0xFFFFu;
        src = (src < (uint32_t)N_NODES) ? src : 0u;                // scalar select
        vv[i] = *(const uint32_t*)(hin + (size_t)src * HID + voff);
      }
      // accumulate: guards here are scalar branches (m, keys all in SGPRs)
      #pragma unroll
      for (int i = 0; i < 16; ++i) {
        if (i >= m) break;
        uint32_t k = sv[i] >> 16;                    // (loc<<3)|rel, scalar
        if (k == cur) {
          uint32_t v = vv[i];
          ax += bf2f(v & 0xFFFFu); ay += bf2f(v >> 16); ++ct;
        } else if (k != kskip) {
          if (cur != 0xFFFFFFFFu) {                  // flush finished group (scalar branch)
            float iv = __builtin_amdgcn_rcpf((float)ct);
            *(uint32_t*)(As + (size_t)(cur >> 3) * LDA + (cur & 7u) * HID + voff) =
                pack2bf(ax * iv, ay * iv);
          }
          if (g + i >= e1) { done = true; cur = 0xFFFFFFFFu; break; }  // next wave's group
          cur = k;
          uint32_t v = vv[i];
          ax = bf2f(v & 0xFFFFu); ay = bf2f(v >> 16); ct = 1;
        }
      }
    }
    if (cur != 0xFFFFFFFFu) {
      float iv = __builtin_amdgcn_rcpf((float)ct);
      *(uint32_t*)(As + (size_t)(cur >> 3) * LDA + (cur & 7u) * HID + voff) =
          pack2bf(ax * iv, ay * iv);
    }
  }
  __syncthreads();

  // ---- phase 2: split-K GEMM. wave (nt,kh): rows 0..32 x cols [nt*16,nt*16+16), K-half kh ----
  f32x4 acc0 = (f32x4){0.f, 0.f, 0.f, 0.f};
  f32x4 acc1 = (f32x4){0.f, 0.f, 0.f, 0.f};
  {
    const uint16_t* apk = As + (size_t)l16 * LDA + quad * 8 + kh * 18 * 32;
    bf16x8 a00 = *(const bf16x8*)(apk);
    bf16x8 a01 = *(const bf16x8*)(apk + 16 * LDA);
    #pragma unroll 1
    for (int kc = 0; kc < 16; kc += 2) {
      bf16x8 nb0 = *(const bf16x8*)(wpk + (size_t)(kc + 2) * 4096);
      bf16x8 na0 = *(const bf16x8*)(apk + (kc + 1) * 32);
      bf16x8 na1 = *(const bf16x8*)(apk + (kc + 1) * 32 + 16 * LDA);
      acc0 = MFMA(a00, b0, acc0);
      acc1 = MFMA(a01, b0, acc1);
      b0 = nb0;
      bf16x8 nb1 = *(const bf16x8*)(wpk + (size_t)(kc + 3) * 4096);
      bf16x8 ma0 = *(const bf16x8*)(apk + (kc + 2) * 32);
      bf16x8 ma1 = *(const bf16x8*)(apk + (kc + 2) * 32 + 16 * LDA);
      acc0 = MFMA(na0, b1, acc0);
      acc1 = MFMA(na1, b1, acc1);
      b1 = nb1; a00 = ma0; a01 = ma1;
    }
    bf16x8 ta0 = *(const bf16x8*)(apk + 17 * 32);
    bf16x8 ta1 = *(const bf16x8*)(apk + 17 * 32 + 16 * LDA);
    acc0 = MFMA(a00, b0, acc0);
    acc1 = MFMA(a01, b0, acc1);
    acc0 = MFMA(ta0, b1, acc0);
    acc1 = MFMA(ta1, b1, acc1);
  }

  // ---- split-K reduce via As reused as scratch (dead after A-reads) ----
  float* scratch = (float*)As;
  __syncthreads();
  if (kh == 1) {
    float* sp = scratch + (size_t)(nt * 2) * 256 + L * 4;
    *(f32x4*)(sp) = acc0;
    *(f32x4*)(sp + 256) = acc1;
  }
  __syncthreads();
  if (kh == 0) {
    const float* sp = scratch + (size_t)(nt * 2) * 256 + L * 4;
    acc0 += *(const f32x4*)(sp);
    acc1 += *(const f32x4*)(sp + 256);

    // epilogue: C/D layout col=lane&15, row=quad*4+reg
    int col = nt * 16 + l16;
    float bv = bias[col];
    if (MODE == 0) {
      #pragma unroll
      for (int rg = 0; rg < 4; ++rg) {
        int row = node0 + quad * 4 + rg;
        if (row < N_NODES)
          ((uint16_t*)hout)[(size_t)row * HID + col] = f2bf(fmaxf(acc0[rg] + bv, 0.f));
      }
      #pragma unroll
      for (int rg = 0; rg < 4; ++rg) {
        int row = node0 + 16 + quad * 4 + rg;
        if (row < N_NODES)
          ((uint16_t*)hout)[(size_t)row * HID + col] = f2bf(fmaxf(acc1[rg] + bv, 0.f));
      }
    } else {
      // fused global-mean-pool partials (sum; divide in k_final)
      bool fast = false;
      int gA = 0;
      if (node0 + BN <= N_NODES) {
        gA = batch[node0];
        int gB = batch[node0 + BN - 1];
        fast = (gA == gB);
      }
      if (fast) {
        float s = 0.f;
        #pragma unroll
        for (int rg = 0; rg < 4; ++rg) s += fmaxf(acc0[rg] + bv, 0.f);
        #pragma unroll
        for (int rg = 0; rg < 4; ++rg) s += fmaxf(acc1[rg] + bv, 0.f);
        s += __shfl_xor(s, 16);
        s += __shfl_xor(s, 32);
        if (quad == 0) atomicAdd(&psum[gA * HID + col], s);
      } else {
        int gp = -1; float run = 0.f;
        #pragma unroll
        for (int k = 0; k < 8; ++k) {
          int rg = k & 3;
          int row = node0 + (k >> 2) * 16 + quad * 4 + rg;
          float v = (k < 4) ? acc0[rg] : acc1[rg];
          if (row < N_NODES) {
            int gg = batch[row];
            if (gg != gp) {
              if (gp >= 0) atomicAdd(&psum[gp * HID + col], run);
              run = 0.f; gp = gg;
            }
            run += fmaxf(v + bv, 0.f);
          }
        }
        if (gp >= 0) atomicAdd(&psum[gp * HID + col], run);
      }
    }
  }
}

__global__ __launch_bounds__(1024) void k_final(const float* __restrict__ psum,
                                                const int* __restrict__ gs, const int* __restrict__ ge,
                                                const float* __restrict__ linW, const float* __restrict__ linb,
                                                float* __restrict__ out) {
  __shared__ float lp[NUM_GRAPHS * HID];       // 32 KB
  __shared__ float lw[HID * NUM_CLASSES];      // 8 KB
  int i = threadIdx.x;
  #pragma unroll
  for (int j = 0; j < 8; ++j) lp[j * 1024 + i] = psum[j * 1024 + i];
  #pragma unroll
  for (int j = 0; j < 2; ++j) lw[j * 1024 + i] = linW[j * 1024 + i];
  __syncthreads();
  int g = i >> 4, c = i & 15;
  float inv = 1.f / fmaxf((float)(ge[g] - gs[g]), 1.f);
  float s = 0.f;
  #pragma unroll 8
  for (int k = 0; k < HID; ++k) s += lp[g * HID + k] * lw[k * NUM_CLASSES + c];
  out[i] = s * inv + linb[c];
}

// ---------- launch ----------
extern "C" void kernel_launch(void* const* d_in, const int* in_sizes, int n_in,
                              void* d_out, int out_size, void* d_ws, size_t ws_size,
                              hipStream_t stream) {
  const float* x     = (const float*)d_in[0];
  const int*   ei    = (const int*)d_in[1];   // [2,E]: [0..E) src, [E..2E) dst
  const int*   et    = (const int*)d_in[2];
  const int*   batch = (const int*)d_in[3];
  const float* W1    = (const float*)d_in[4];
  const float* root1 = (const float*)d_in[5];
  const float* b1    = (const float*)d_in[6];
  const float* W2    = (const float*)d_in[7];
  const float* root2 = (const float*)d_in[8];
  const float* b2    = (const float*)d_in[9];
  const float* linW  = (const float*)d_in[10];
  const float* linb  = (const float*)d_in[11];
  float* out = (float*)d_out;

  char* ws = (char*)d_ws;
  size_t off = 0;
  auto alloc = [&](size_t bytes) -> char* {
    char* p = ws + off;
    off += (bytes + 255) & ~(size_t)255;
    return p;
  };
  // zero-region: deg8 | gb | psum (contiguous, one memset)
  int*      deg8  = (int*)alloc((size_t)N8 * 4);
  int*      gb    = (int*)alloc(2 * NUM_GRAPHS * 4);
  float*    psum  = (float*)alloc((size_t)NUM_GRAPHS * HID * 4);
  size_t zbytes = (size_t)N8 * 4 + 512 + (size_t)NUM_GRAPHS * HID * 4;
  int*      gs    = gb;
  int*      ge    = gb + NUM_GRAPHS;
  int*      offs8 = (int*)alloc((size_t)(N8 + 1) * 4);
  int*      nxt   = (int*)alloc((size_t)N8 * 4);
  int*      bsum  = (int*)alloc(512 * 4);
  uint32_t* epack = (uint32_t*)alloc((size_t)(N_EDGES + 64) * 4);   // +64: prefetch overrun pad
  uint16_t* Wf1   = (uint16_t*)alloc((size_t)KOUT * KIN * 2);
  uint16_t* Wf2   = (uint16_t*)alloc((size_t)KOUT * KIN * 2);
  uint16_t* xb    = (uint16_t*)alloc((size_t)N_NODES * HID * 2);
  uint16_t* h1b   = (uint16_t*)alloc((size_t)N_NODES * HID * 2);

  hipMemsetAsync(deg8, 0, zbytes, stream);

  int nb = (N8 + 1023) / 1024;          // 391
  k_prep<<<HIST_B + BND_B + WP_B + CVT_B, 256, 0, stream>>>(
      ei, et, deg8, batch, gs, ge, W1, root1, Wf1, W2, root2, Wf2, x, xb);
  k_scan1<<<nb, 256, 0, stream>>>(deg8, offs8, bsum);
  k_scan23<<<(N8 + 255) / 256, 256, 0, stream>>>(offs8, nxt, bsum, nb);
  k_scatter<<<(N_EDGES + 255) / 256, 256, 0, stream>>>(ei, et, nxt, epack);

  // fused layers: sorted-stream aggregate -> As[32,1152] in LDS -> split-K MFMA with Wcat
  k_fused<0><<<NBLK, 1024, 0, stream>>>(xb,  epack, offs8, Wf1, b1, h1b, nullptr, nullptr);
  k_fused<1><<<NBLK, 1024, 0, stream>>>(h1b, epack, offs8, Wf2, b2, nullptr, psum, batch);

  k_final<<<1, 1024, 0, stream>>>(psum, gs, ge, linW, linb, out);
}